// Round 6
// baseline (2224.815 us; speedup 1.0000x reference)
//
#include <hip/hip_runtime.h>
#include <hip/hip_fp16.h>

// Problem dims (fixed)
#define Bc 128   // batch
#define Tc 128   // timesteps
#define Nc 128   // driving series
#define Mc 256   // hidden
#define G4 1024  // 4*M

typedef _Float16 half8 __attribute__((ext_vector_type(8)));
typedef float f32x4 __attribute__((ext_vector_type(4)));
typedef unsigned u32x4 __attribute__((ext_vector_type(4)));

__device__ __forceinline__ float frcp(float x) {
#if __has_builtin(__builtin_amdgcn_rcpf)
  return __builtin_amdgcn_rcpf(x);
#else
  return 1.f / x;
#endif
}
__device__ __forceinline__ float fsig(float x) { return frcp(1.f + __expf(-x)); }
__device__ __forceinline__ float ftanh(float x) {
  float t = __expf(2.f * x);
  return 1.f - 2.f * frcp(t + 1.f);
}

// ---- inline-asm memory ops (all loop VMEM is asm so the vmcnt ledger is exact)
// NOTE gfx950 syntax: offset:N must PRECEDE the cache flags (sc0 sc1).
#define LDX4CC(dst, ptr, OFF) \
  asm volatile("global_load_dwordx4 %0, %1, off offset:" #OFF " sc0 sc1" \
               : "=&v"(dst) : "v"(ptr))
#define LDX4P(dst, ptr, OFF) \
  asm volatile("global_load_dwordx4 %0, %1, off offset:" #OFF \
               : "=&v"(dst) : "v"(ptr))
#define STHCC(ptr, v_, OFF) \
  asm volatile("global_store_short %0, %1, off offset:" #OFF " sc0 sc1" \
               :: "v"(ptr), "v"(v_))
#define STHP(ptr, v_, OFF) \
  asm volatile("global_store_short %0, %1, off offset:" #OFF \
               :: "v"(ptr), "v"(v_))
#define STBCC(ptr, v_, OFF) \
  asm volatile("global_store_byte %0, %1, off offset:" #OFF " sc0 sc1" \
               :: "v"(ptr), "v"(v_))
#define VMCNT(N) do { asm volatile("s_waitcnt vmcnt(" #N ")" ::: "memory"); \
                      __builtin_amdgcn_sched_barrier(0); } while (0)

// ---------------------------------------------------------------------------
// k_prep: (a) pack Wh into fp16 MFMA A-fragments with gate-interleaved column
// permutation j' = 4*mcol + g; (b) zero flags region; (c) hx[0] = fp16(h0).
// ---------------------------------------------------------------------------
__global__ void k_prep(const float* __restrict__ Wh, const float* __restrict__ h0,
                       __half* __restrict__ wht, __half* __restrict__ hx,
                       unsigned* __restrict__ flags) {
  int bid = blockIdx.x;
  if (bid < 512) {
    int i = bid * 256 + threadIdx.x;       // u32 index in [0, 131072)
    int jt = i >> 11;
    int rem = i & 2047;
    int kt = rem >> 8;
    int rem2 = rem & 255;
    int lane = rem2 >> 2;
    int r2 = rem2 & 3;
    int jp = jt * 16 + (lane & 15);        // permuted col j'
    int g = jp & 3, mcol = jp >> 2;
    int j = g * 256 + mcol;                // original Wh column
    int mk0 = kt * 32 + (lane >> 4) * 8 + 2 * r2;
    wht[(size_t)i * 2]     = __float2half(Wh[(size_t)mk0 * G4 + j]);
    wht[(size_t)i * 2 + 1] = __float2half(Wh[(size_t)(mk0 + 1) * G4 + j]);
  } else {
    for (int i = threadIdx.x; i < 8 * 4096; i += 256) flags[i] = 0u;
    for (int i = threadIdx.x; i < Bc * Mc; i += 256) hx[i] = __float2half(h0[i]);
  }
}

// ---------------------------------------------------------------------------
// k_ux: PX[b][u][n] = exp(2*(sum_t X[b][t][n]*Ud[t][u] + bU[u]))
// ---------------------------------------------------------------------------
__global__ void k_ux(const float* __restrict__ X, const float* __restrict__ Ud,
                     const float* __restrict__ bU, float* __restrict__ PX) {
  __shared__ float Xl[Tc][Nc];  // 64KB
  int b = blockIdx.x;
  const float* Xb = X + (size_t)b * Tc * Nc;
  for (int i = threadIdx.x; i < Tc * Nc; i += 256) Xl[i >> 7][i & 127] = Xb[i];
  __syncthreads();
  int n = threadIdx.x & 127;
  int uh = __builtin_amdgcn_readfirstlane(threadIdx.x >> 7);
  for (int u0 = uh * 64; u0 < uh * 64 + 64; u0 += 8) {
    float acc[8];
#pragma unroll
    for (int i = 0; i < 8; i++) acc[i] = 0.f;
    for (int tt = 0; tt < Tc; ++tt) {
      float xv = Xl[tt][n];
#pragma unroll
      for (int i = 0; i < 8; i++) acc[i] += xv * Ud[tt * Tc + u0 + i];
    }
#pragma unroll
    for (int i = 0; i < 8; i++)
      PX[((size_t)b * Tc + (u0 + i)) * Nc + n] = __expf(2.f * (acc[i] + bU[u0 + i]));
  }
}

// ---------------------------------------------------------------------------
// k_xwx2: XWxP[t][b][j'] with j' = 4m+g. grid 512 = t(128) x bq(4), 256 thr.
// ---------------------------------------------------------------------------
__global__ __launch_bounds__(256, 2)
void k_xwx2(const float* __restrict__ X, const float* __restrict__ Wx,
            const float* __restrict__ bias, float* __restrict__ XWxP) {
  __shared__ float xl[32][Nc];  // 16KB
  int t = blockIdx.x >> 2;
  int b0 = (blockIdx.x & 3) * 32;
  for (int i = threadIdx.x; i < 32 * Nc; i += 256) {
    int row = i >> 7, n = i & 127;
    xl[row][n] = X[(size_t)(b0 + row) * Tc * Nc + (size_t)t * Nc + n];
  }
  __syncthreads();
  int m = threadIdx.x;
  float acc[32][4];
#pragma unroll
  for (int i = 0; i < 32; i++)
#pragma unroll
    for (int g = 0; g < 4; g++) acc[i][g] = 0.f;
  for (int n = 0; n < Nc; ++n) {
    float wi = Wx[(size_t)n * G4 + m];
    float wf = Wx[(size_t)n * G4 + 256 + m];
    float wg = Wx[(size_t)n * G4 + 512 + m];
    float wo = Wx[(size_t)n * G4 + 768 + m];
#pragma unroll
    for (int i = 0; i < 32; i++) {
      float xv = xl[i][n];
      acc[i][0] += xv * wi; acc[i][1] += xv * wf;
      acc[i][2] += xv * wg; acc[i][3] += xv * wo;
    }
  }
  float bi = bias[m], bf = bias[256 + m], bg = bias[512 + m], bo = bias[768 + m];
#pragma unroll
  for (int i = 0; i < 32; i++) {
    float4 o;
    o.x = acc[i][0] + bi; o.y = acc[i][1] + bf;
    o.z = acc[i][2] + bg; o.w = acc[i][3] + bo;
    *(float4*)(XWxP + ((size_t)t * Bc + b0 + i) * G4 + m * 4) = o;
  }
}

// ---------------------------------------------------------------------------
// k_scan: persistent LSTM scan, 8 blocks x 512 threads.
// Block (set = bid>>2, q = bid&3) owns columns j' in [q*256,(q+1)*256) for
// FOUR batch-groups g = set*4 .. set*4+3 (16 batches each), processed as 4
// pipelined slots per t-round.  All sync is sc0sc1 (IF$-coherent, proven in
// r3) with per-wave byte flags and a fully counted vmcnt ledger:
//   per slot issues (per WAVE; vmcnt is per-wave, flag store is exec-masked
//   but still one wave-level VMEM op): 2 poll + 8 h + 2 xwx loads,
//   1 flag byte, 2+2 stores = 17.
//   steady state: 34 outstanding -> s_waitcnt vmcnt(17) drains exactly
//   {flag+4 stores of slot k-2, 12 loads of slot k-1 (= current group)}.
// Flag for group g's h[t+1] is stored 2 slots after its stores (ack proven by
// the ledger); consumers check 2 slots later -> ~1700cy gap > ~900cy IF$
// propagation -> polls hit first try; retry path drains vmcnt(0) (safe).
// ---------------------------------------------------------------------------
#define SLOT(G, GN, PO0, PO1, CO0, CO1, FOFF, X3) \
  { \
    constexpr int cb_ = (G) & 1, nb_ = ((G) + 1) & 1; \
    const char* hB_ = hp[GN] + ((X3) ? 65536 : 0); \
    const char* xB_ = xp[GN] + ((X3) ? xadv : 0); \
    asm volatile("global_load_dwordx4 %0, %2, off offset:" #PO0 " sc0 sc1\n\t" \
                 "global_load_dwordx4 %1, %2, off offset:" #PO1 " sc0 sc1" \
                 : "=&v"(pv[nb_][0]), "=&v"(pv[nb_][1]) : "v"(dp)); \
    LDX4CC(hbuf[nb_][0], hB_, 0);   LDX4CC(hbuf[nb_][1], hB_, 64); \
    LDX4CC(hbuf[nb_][2], hB_, 128); LDX4CC(hbuf[nb_][3], hB_, 192); \
    LDX4CC(hbuf[nb_][4], hB_, 256); LDX4CC(hbuf[nb_][5], hB_, 320); \
    LDX4CC(hbuf[nb_][6], hB_, 384); LDX4CC(hbuf[nb_][7], hB_, 448); \
    LDX4P(xbuf[nb_][0], xB_, 0);    LDX4P(xbuf[nb_][1], xB_, 64); \
    if ((G) == 0 && t == 0) { VMCNT(12); } else { VMCNT(17); } \
    if (t > 0) { \
      u32x4 pa_ = pv[cb_][0], pb_ = pv[cb_][1]; \
      while ((pa_.x & pa_.y & pa_.z & pa_.w & pb_.x & pb_.y & pb_.z & pb_.w) \
             != 0x01010101u) { \
        asm volatile("global_load_dwordx4 %0, %2, off offset:" #CO0 " sc0 sc1\n\t" \
                     "global_load_dwordx4 %1, %2, off offset:" #CO1 " sc0 sc1\n\t" \
                     "s_waitcnt vmcnt(0)" \
                     : "=&v"(pa_), "=&v"(pb_) : "v"(dp) : "memory"); \
      } \
    } \
    if (lane == 0) STBCC(fp, onev, FOFF); \
    f32x4 acc0_ = xbuf[cb_][0], acc1_ = xbuf[cb_][1]; \
    _Pragma("unroll") \
    for (int kt = 0; kt < 8; ++kt) { \
      half8 Bf_ = __builtin_bit_cast(half8, hbuf[cb_][kt]); \
      acc0_ = __builtin_amdgcn_mfma_f32_16x16x32_f16(A[0][kt], Bf_, acc0_, 0, 0, 0); \
      acc1_ = __builtin_amdgcn_mfma_f32_16x16x32_f16(A[1][kt], Bf_, acc1_, 0, 0, 0); \
    } \
    float i0_ = fsig(acc0_[0]), f0_ = fsig(acc0_[1]); \
    float g0_ = ftanh(acc0_[2]), o0_ = fsig(acc0_[3]); \
    c0g[G] = f0_ * c0g[G] + i0_ * g0_; \
    float h0_ = o0_ * ftanh(c0g[G]); \
    float i1_ = fsig(acc1_[0]), f1_ = fsig(acc1_[1]); \
    float g1_ = ftanh(acc1_[2]), o1_ = fsig(acc1_[3]); \
    c1g[G] = f1_ * c1g[G] + i1_ * g1_; \
    float h1_ = o1_ * ftanh(c1g[G]); \
    char* hs_ = (char*)hp[G] + hsoff; \
    STHCC(hs_, (unsigned)__half_as_ushort(__float2half(h0_)), 0); \
    STHCC(hs_, (unsigned)__half_as_ushort(__float2half(h1_)), 8); \
    char* cs_ = hs_ + cdel; \
    STHP(cs_, (unsigned)__half_as_ushort(__float2half(c0g[G])), 0); \
    STHP(cs_, (unsigned)__half_as_ushort(__float2half(c1g[G])), 8); \
  }

__global__ __launch_bounds__(512, 2)
void k_scan(const __half* __restrict__ wht, const float* __restrict__ xwxp,
            __half* __restrict__ hx, __half* __restrict__ cx,
            unsigned* __restrict__ flags, const float* __restrict__ s0) {
  int bid = blockIdx.x;                 // 8 blocks
  int set = bid >> 2, q = bid & 3;
  int tid = threadIdx.x;
  int wave = __builtin_amdgcn_readfirstlane(tid >> 6);
  int lane = tid & 63;
  int lb = lane & 15, lg = lane >> 4;
  int jt0 = q * 16 + wave * 2;
  int m0 = jt0 * 4 + lg;

  // persistent A fragments: 64 VGPRs (plain loads, drained before the ledger)
  half8 A[2][8];
#pragma unroll
  for (int u = 0; u < 2; ++u)
#pragma unroll
    for (int kt = 0; kt < 8; ++kt)
      A[u][kt] = *(const half8*)(wht + ((size_t)((jt0 + u) * 8 + kt) * 64 + lane) * 8);

  float c0g[4], c1g[4];
  const char* hp[4];
  const char* xp[4];
#pragma unroll
  for (int g = 0; g < 4; ++g) {
    int bg = set * 64 + g * 16 + lb;
    c0g[g] = s0[(size_t)bg * Mc + m0];
    c1g[g] = s0[(size_t)bg * Mc + m0 + 4];
    hp[g] = (const char*)hx + (size_t)(bg * Mc + lg * 8) * 2;
    xp[g] = (const char*)xwxp + (size_t)(bg * G4 + jt0 * 16 + lg * 4) * 4;
  }
  const char* dp = (const char*)flags + set * 16512;  // done[t][g][q][wave] bytes
  char* fp = (char*)flags + set * 16512 + q * 8 + wave;
  const int hsoff = 65536 + (jt0 * 4 - 7 * lg) * 2;   // h-store offset from hp[g]
  const ptrdiff_t cdel = (const char*)cx - (const char*)hx - 65536;
  unsigned onev = 1u;

  f32x4 hbuf[2][8];
  f32x4 xbuf[2][2];
  u32x4 pv[2][2];

  // drain all compiler-issued VMEM, then seed the pipeline (poll0 + ld0 = 12)
  asm volatile("s_waitcnt vmcnt(0)" ::: "memory");
  __builtin_amdgcn_sched_barrier(0);
  asm volatile("global_load_dwordx4 %0, %2, off offset:0 sc0 sc1\n\t"
               "global_load_dwordx4 %1, %2, off offset:16 sc0 sc1"
               : "=&v"(pv[0][0]), "=&v"(pv[0][1]) : "v"(dp));
  LDX4CC(hbuf[0][0], hp[0], 0);   LDX4CC(hbuf[0][1], hp[0], 64);
  LDX4CC(hbuf[0][2], hp[0], 128); LDX4CC(hbuf[0][3], hp[0], 192);
  LDX4CC(hbuf[0][4], hp[0], 256); LDX4CC(hbuf[0][5], hp[0], 320);
  LDX4CC(hbuf[0][6], hp[0], 384); LDX4CC(hbuf[0][7], hp[0], 448);
  LDX4P(xbuf[0][0], xp[0], 0);    LDX4P(xbuf[0][1], xp[0], 64);

#pragma unroll 1
  for (int t = 0; t < 128; ++t) {
    const long xadv = (t < 127) ? 524288 : 0;  // don't read past XWxP at t=127
    SLOT(0, 1,  32,  48,   0,  16,  64, 0)
    SLOT(1, 2,  64,  80,  32,  48,  96, 0)
    SLOT(2, 3,  96, 112,  64,  80, 128, 0)
    SLOT(3, 0, 128, 144,  96, 112, 160, 1)
    hp[0] += 65536; hp[1] += 65536; hp[2] += 65536; hp[3] += 65536;
    xp[0] += 524288; xp[1] += 524288; xp[2] += 524288; xp[3] += 524288;
    dp += 128; fp += 128;
  }
}

// ---------------------------------------------------------------------------
// k_wall2: Wall[t*B+b][u] = [h;c] @ Wd + bW (h,c as fp16)
// ---------------------------------------------------------------------------
__global__ void k_wall2(const __half2* __restrict__ Hx2, const __half2* __restrict__ Cx2,
                        const float* __restrict__ Wd, const float* __restrict__ bW,
                        float* __restrict__ Wall) {
  int r0 = blockIdx.x * 32;
  int wv = __builtin_amdgcn_readfirstlane(threadIdx.x >> 6);
  int lane = threadIdx.x & 63;
  int u2 = lane * 2;
  int rbase = r0 + wv * 8;
  float acc[8][2];
#pragma unroll
  for (int i = 0; i < 8; i++) { acc[i][0] = 0.f; acc[i][1] = 0.f; }
#pragma unroll 2
  for (int k2 = 0; k2 < 128; ++k2) {
    float2 wh0 = *(const float2*)(Wd + (size_t)(2 * k2) * Tc + u2);
    float2 wh1 = *(const float2*)(Wd + (size_t)(2 * k2 + 1) * Tc + u2);
    float2 wc0 = *(const float2*)(Wd + (size_t)(Mc + 2 * k2) * Tc + u2);
    float2 wc1 = *(const float2*)(Wd + (size_t)(Mc + 2 * k2 + 1) * Tc + u2);
#pragma unroll
    for (int i = 0; i < 8; i++) {
      __half2 hv = Hx2[(size_t)(rbase + i) * 128 + 16384 + k2];  // slot t+1
      __half2 cv = Cx2[(size_t)(rbase + i) * 128 + k2];
      float hlo = __low2float(hv), hhi = __high2float(hv);
      float clo = __low2float(cv), chi = __high2float(cv);
      acc[i][0] += hlo * wh0.x + hhi * wh1.x + clo * wc0.x + chi * wc1.x;
      acc[i][1] += hlo * wh0.y + hhi * wh1.y + clo * wc0.y + chi * wc1.y;
    }
  }
  float bw0 = bW[u2], bw1 = bW[u2 + 1];
#pragma unroll
  for (int i = 0; i < 8; i++) {
    float2 o; o.x = acc[i][0] + bw0; o.y = acc[i][1] + bw1;
    *(float2*)(Wall + (size_t)(rbase + i) * Tc + u2) = o;
  }
}

// ---------------------------------------------------------------------------
// k_attn: logits_n = sum_u (-2 v_u) / (A_u * P_un + 1); softmax; out = X*alpha
// ---------------------------------------------------------------------------
__global__ void k_attn(const float* __restrict__ Wall, const float* __restrict__ PX,
                       const float* __restrict__ vd, const float* __restrict__ X,
                       float* __restrict__ out) {
  __shared__ float4 av[Nc];
  __shared__ float v2s[Nc];
  __shared__ float wred[2][4];
  int b = blockIdx.x & 127, tq = blockIdx.x >> 7;
  int n = threadIdx.x;           // 0..127
  int wv = n >> 6;
  float4 a;
  a.x = __expf(2.f * Wall[((size_t)(tq * 4 + 0) * Bc + b) * Tc + n]);
  a.y = __expf(2.f * Wall[((size_t)(tq * 4 + 1) * Bc + b) * Tc + n]);
  a.z = __expf(2.f * Wall[((size_t)(tq * 4 + 2) * Bc + b) * Tc + n]);
  a.w = __expf(2.f * Wall[((size_t)(tq * 4 + 3) * Bc + b) * Tc + n]);
  av[n] = a;
  v2s[n] = -2.f * vd[n];
  __syncthreads();
  const float* Pb = PX + (size_t)b * Tc * Nc;
  float e0 = 0.f, e1 = 0.f, e2 = 0.f, e3 = 0.f;
#pragma unroll 4
  for (int u = 0; u < Tc; ++u) {
    float P = Pb[(size_t)u * Nc + n];
    float4 au = av[u];
    float v2 = v2s[u];
    e0 = fmaf(v2, frcp(fmaf(au.x, P, 1.f)), e0);
    e1 = fmaf(v2, frcp(fmaf(au.y, P, 1.f)), e1);
    e2 = fmaf(v2, frcp(fmaf(au.z, P, 1.f)), e2);
    e3 = fmaf(v2, frcp(fmaf(au.w, P, 1.f)), e3);
  }
  float e[4] = {e0, e1, e2, e3};
  float M[4], S[4], ex[4];
#pragma unroll
  for (int k = 0; k < 4; ++k) {
    float m = e[k];
#pragma unroll
    for (int off = 32; off > 0; off >>= 1) m = fmaxf(m, __shfl_xor(m, off));
    if ((n & 63) == 0) wred[wv][k] = m;
  }
  __syncthreads();
#pragma unroll
  for (int k = 0; k < 4; ++k) M[k] = fmaxf(wred[0][k], wred[1][k]);
  __syncthreads();
#pragma unroll
  for (int k = 0; k < 4; ++k) {
    ex[k] = __expf(e[k] - M[k]);
    float s = ex[k];
#pragma unroll
    for (int off = 32; off > 0; off >>= 1) s += __shfl_xor(s, off);
    if ((n & 63) == 0) wred[wv][k] = s;
  }
  __syncthreads();
#pragma unroll
  for (int k = 0; k < 4; ++k) S[k] = wred[0][k] + wred[1][k];
#pragma unroll
  for (int k = 0; k < 4; ++k) {
    int t = tq * 4 + k;
    size_t xi = ((size_t)b * Tc + t) * Nc + n;
    out[xi] = X[xi] * (ex[k] * frcp(S[k]));
  }
}

extern "C" void kernel_launch(void* const* d_in, const int* in_sizes, int n_in,
                              void* d_out, int out_size, void* d_ws, size_t ws_size,
                              hipStream_t stream) {
  (void)in_sizes; (void)n_in; (void)out_size; (void)ws_size;
  const float* X  = (const float*)d_in[0];
  const float* h0 = (const float*)d_in[1];
  const float* s0 = (const float*)d_in[2];
  const float* Wx = (const float*)d_in[3];
  const float* Wh = (const float*)d_in[4];
  const float* bb = (const float*)d_in[5];
  const float* Wd = (const float*)d_in[6];
  const float* bW = (const float*)d_in[7];
  const float* Ud = (const float*)d_in[8];
  const float* bU = (const float*)d_in[9];
  const float* vd = (const float*)d_in[10];
  // d_in[11] = bv: softmax(x + const) == softmax(x), no effect on output.
  float* out = (float*)d_out;
  float* ws = (float*)d_ws;

  float* PX   = ws;                          //  2,097,152 f
  float* XWxP = PX + 2097152;                // 16,777,216 f
  __half* hx  = (__half*)(XWxP + 16777216);  // 129*32768 halves
  __half* cx  = hx + 129 * 32768;            // 128*32768 halves
  float* Wall = (float*)(cx + 128 * 32768);  //  2,097,152 f
  __half* wht = (__half*)(Wall + 2097152);   //   262,144 halves
  unsigned* flags = (unsigned*)(wht + 262144); // 8*4096 u32 (done bytes)
  // total ~101 MB

  k_prep<<<513, 256, 0, stream>>>(Wh, h0, wht, hx, flags);
  k_ux<<<Bc, 256, 0, stream>>>(X, Ud, bU, PX);
  k_xwx2<<<Tc * 4, 256, 0, stream>>>(X, Wx, bb, XWxP);
  k_scan<<<8, 512, 0, stream>>>(wht, XWxP, hx, cx, flags, s0);
  k_wall2<<<(Tc * Bc) / 32, 256, 0, stream>>>((const __half2*)hx, (const __half2*)cx,
                                              Wd, bW, Wall);
  k_attn<<<Bc * 32, 128, 0, stream>>>(Wall, PX, vd, X, out);
}

// Round 7
// 931.002 us; speedup vs baseline: 2.3897x; 2.3897x over previous
//
#include <hip/hip_runtime.h>
#include <hip/hip_fp16.h>

// Problem dims (fixed)
#define Bc 128   // batch
#define Tc 128   // timesteps
#define Nc 128   // driving series
#define Mc 256   // hidden
#define G4 1024  // 4*M

typedef _Float16 half8 __attribute__((ext_vector_type(8)));
typedef float f32x4 __attribute__((ext_vector_type(4)));
typedef unsigned u32x4 __attribute__((ext_vector_type(4)));

__device__ __forceinline__ float frcp(float x) {
#if __has_builtin(__builtin_amdgcn_rcpf)
  return __builtin_amdgcn_rcpf(x);
#else
  return 1.f / x;
#endif
}
__device__ __forceinline__ float fsig(float x) { return frcp(1.f + __expf(-x)); }
__device__ __forceinline__ float ftanh(float x) {
  float t = __expf(2.f * x);
  return 1.f - 2.f * frcp(t + 1.f);
}

// gfx950: offset:N must precede cache flags
#define LDX4CC(dst, ptr, OFF) \
  asm volatile("global_load_dwordx4 %0, %1, off offset:" #OFF " sc0 sc1" \
               : "=v"(dst) : "v"(ptr))
#define STDWCC(ptr, v_) \
  asm volatile("global_store_dword %0, %1, off sc0 sc1" :: "v"(ptr), "v"(v_))
#define VMCNT0 do { asm volatile("s_waitcnt vmcnt(0)" ::: "memory"); \
                    __builtin_amdgcn_sched_barrier(0); } while (0)

// ---------------------------------------------------------------------------
// k_prep (8768 blocks x 256):
//  bid<512   : pack Wh -> fp16 A-frags, gate-interleaved cols j'=4m+g, and
//              k-pair order (r2, r2+4) matching the B-side u32 (m, m+4) pairs.
//  512..575  : hx2[0] = ~pack(fp16(h0))  (u32 i=4a+d <-> halves (8a+d, 8a+d+4))
//  576..8767 : zero hx2[1..128]  (poll sentinel; re-zeroed EVERY launch)
// ---------------------------------------------------------------------------
__global__ void k_prep(const float* __restrict__ Wh, const float* __restrict__ h0,
                       __half* __restrict__ wht, unsigned* __restrict__ hx2) {
  int bid = blockIdx.x;
  if (bid < 512) {
    int i = bid * 256 + threadIdx.x;       // u32 index in [0, 131072)
    int jt = i >> 11;
    int rem = i & 2047;
    int kt = rem >> 8;
    int rem2 = rem & 255;
    int lane = rem2 >> 2;
    int r2 = rem2 & 3;
    int jp = jt * 16 + (lane & 15);        // permuted col j'
    int g = jp & 3, mcol = jp >> 2;
    int j = g * 256 + mcol;                // original Wh column
    int mk0 = kt * 32 + (lane >> 4) * 8 + r2;   // k-pair (r2, r2+4)
    wht[(size_t)i * 2]     = __float2half(Wh[(size_t)mk0 * G4 + j]);
    wht[(size_t)i * 2 + 1] = __float2half(Wh[(size_t)(mk0 + 4) * G4 + j]);
  } else if (bid < 576) {
    int idx = (bid - 512) * 256 + threadIdx.x;   // 0..16383
    int b = idx >> 7, i = idx & 127;
    int a = i >> 2, d = i & 3;
    unsigned lo = __half_as_ushort(__float2half(h0[(size_t)b * Mc + 8 * a + d]));
    unsigned hi = __half_as_ushort(__float2half(h0[(size_t)b * Mc + 8 * a + d + 4]));
    hx2[idx] = ~(lo | (hi << 16));
  } else {
    int idx = (bid - 576) * 256 + threadIdx.x;   // 0..2097151
    hx2[16384 + idx] = 0u;
  }
}

// ---------------------------------------------------------------------------
// k_ux: PX[b][u][n] = exp(2*(sum_t X[b][t][n]*Ud[t][u] + bU[u]))
// ---------------------------------------------------------------------------
__global__ void k_ux(const float* __restrict__ X, const float* __restrict__ Ud,
                     const float* __restrict__ bU, float* __restrict__ PX) {
  __shared__ float Xl[Tc][Nc];  // 64KB
  int b = blockIdx.x;
  const float* Xb = X + (size_t)b * Tc * Nc;
  for (int i = threadIdx.x; i < Tc * Nc; i += 256) Xl[i >> 7][i & 127] = Xb[i];
  __syncthreads();
  int n = threadIdx.x & 127;
  int uh = __builtin_amdgcn_readfirstlane(threadIdx.x >> 7);
  for (int u0 = uh * 64; u0 < uh * 64 + 64; u0 += 8) {
    float acc[8];
#pragma unroll
    for (int i = 0; i < 8; i++) acc[i] = 0.f;
    for (int tt = 0; tt < Tc; ++tt) {
      float xv = Xl[tt][n];
#pragma unroll
      for (int i = 0; i < 8; i++) acc[i] += xv * Ud[tt * Tc + u0 + i];
    }
#pragma unroll
    for (int i = 0; i < 8; i++)
      PX[((size_t)b * Tc + (u0 + i)) * Nc + n] = __expf(2.f * (acc[i] + bU[u0 + i]));
  }
}

// ---------------------------------------------------------------------------
// k_xwx2: XWxP[t][b][j'] with j' = 4m+g. grid 512 = t(128) x bq(4), 256 thr.
// ---------------------------------------------------------------------------
__global__ __launch_bounds__(256, 2)
void k_xwx2(const float* __restrict__ X, const float* __restrict__ Wx,
            const float* __restrict__ bias, float* __restrict__ XWxP) {
  __shared__ float xl[32][Nc];  // 16KB
  int t = blockIdx.x >> 2;
  int b0 = (blockIdx.x & 3) * 32;
  for (int i = threadIdx.x; i < 32 * Nc; i += 256) {
    int row = i >> 7, n = i & 127;
    xl[row][n] = X[(size_t)(b0 + row) * Tc * Nc + (size_t)t * Nc + n];
  }
  __syncthreads();
  int m = threadIdx.x;
  float acc[32][4];
#pragma unroll
  for (int i = 0; i < 32; i++)
#pragma unroll
    for (int g = 0; g < 4; g++) acc[i][g] = 0.f;
  for (int n = 0; n < Nc; ++n) {
    float wi = Wx[(size_t)n * G4 + m];
    float wf = Wx[(size_t)n * G4 + 256 + m];
    float wg = Wx[(size_t)n * G4 + 512 + m];
    float wo = Wx[(size_t)n * G4 + 768 + m];
#pragma unroll
    for (int i = 0; i < 32; i++) {
      float xv = xl[i][n];
      acc[i][0] += xv * wi; acc[i][1] += xv * wf;
      acc[i][2] += xv * wg; acc[i][3] += xv * wo;
    }
  }
  float bi = bias[m], bf = bias[256 + m], bg = bias[512 + m], bo = bias[768 + m];
#pragma unroll
  for (int i = 0; i < 32; i++) {
    float4 o;
    o.x = acc[i][0] + bi; o.y = acc[i][1] + bf;
    o.z = acc[i][2] + bg; o.w = acc[i][3] + bo;
    *(float4*)(XWxP + ((size_t)t * Bc + b0 + i) * G4 + m * 4) = o;
  }
}

// ---------------------------------------------------------------------------
// k_scan: persistent LSTM scan, 32 blocks x 512 threads. DATA-IS-FLAG sync:
// h stored as ONE dword/lane = ~( h[m] | h[m+4]<<16 ) at hx2[t+1][b][jt0*2+lg]
// via sc0sc1 (IF$); slot pre-zeroed; consumer polls its 8 dwordx4 sc0sc1
// loads until every dword != 0, then uses ~data. No flags, no atomics, no
// producer-side wait, no barriers. ~pack==0 would require NaN h: impossible.
// A/B k-pair order (r2, r2+4) is consistent on both sides (perm-invariant).
// ---------------------------------------------------------------------------
__global__ __launch_bounds__(512, 1)
void k_scan(const __half* __restrict__ wht, const float* __restrict__ xwxp,
            unsigned* __restrict__ hx2, __half* __restrict__ cx,
            const float* __restrict__ s0) {
  int bid = blockIdx.x;                 // 32 blocks
  int q = bid >> 3, grp = bid & 7;
  int tid = threadIdx.x;
  int wave = __builtin_amdgcn_readfirstlane(tid >> 6);
  int lane = tid & 63;
  int lb = lane & 15, lg = lane >> 4;
  int b = grp * 16 + lb;
  int jt0 = q * 16 + wave * 2;          // even
  int m0 = jt0 * 4 + lg;

  // persistent A fragments: 64 VGPRs
  half8 A[2][8];
#pragma unroll
  for (int u = 0; u < 2; ++u)
#pragma unroll
    for (int kt = 0; kt < 8; ++kt)
      A[u][kt] = *(const half8*)(wht + ((size_t)((jt0 + u) * 8 + kt) * 64 + lane) * 8);

  float c0 = s0[(size_t)b * Mc + m0];
  float c1 = s0[(size_t)b * Mc + m0 + 4];

  const char* hq = (const char*)hx2 + ((size_t)b * 128 + lg * 4) * 4;       // read h[t]
  char*       hs = (char*)hx2 + ((size_t)16384 + b * 128 + jt0 * 2 + lg) * 4; // write h[t+1]
  const float* xq = xwxp + ((size_t)b) * G4 + jt0 * 16 + lg * 4;
  __half*      cq = cx + (size_t)b * Mc;

  f32x4 braw[8];

#pragma unroll 1
  for (int t = 0; t < 128; ++t) {
    // acc init (plain loads, L2)
    f32x4 acc0 = *(const f32x4*)(xq);
    f32x4 acc1 = *(const f32x4*)(xq + 16);

    // poll-load h[t]: data IS the flag
    LDX4CC(braw[0], hq, 0);   LDX4CC(braw[1], hq, 64);
    LDX4CC(braw[2], hq, 128); LDX4CC(braw[3], hq, 192);
    LDX4CC(braw[4], hq, 256); LDX4CC(braw[5], hq, 320);
    LDX4CC(braw[6], hq, 384); LDX4CC(braw[7], hq, 448);
    for (;;) {
      VMCNT0;
      unsigned mn = 0xFFFFFFFFu;
#pragma unroll
      for (int kt = 0; kt < 8; ++kt) {
        u32x4 u = __builtin_bit_cast(u32x4, braw[kt]);
        mn = min(mn, min(min(u.x, u.y), min(u.z, u.w)));
      }
      if (__builtin_expect(mn != 0u, 1)) break;
      LDX4CC(braw[0], hq, 0);   LDX4CC(braw[1], hq, 64);
      LDX4CC(braw[2], hq, 128); LDX4CC(braw[3], hq, 192);
      LDX4CC(braw[4], hq, 256); LDX4CC(braw[5], hq, 320);
      LDX4CC(braw[6], hq, 384); LDX4CC(braw[7], hq, 448);
    }

#pragma unroll
    for (int kt = 0; kt < 8; ++kt) {
      u32x4 u = ~__builtin_bit_cast(u32x4, braw[kt]);
      half8 Bf = __builtin_bit_cast(half8, u);
      acc0 = __builtin_amdgcn_mfma_f32_16x16x32_f16(A[0][kt], Bf, acc0, 0, 0, 0);
      acc1 = __builtin_amdgcn_mfma_f32_16x16x32_f16(A[1][kt], Bf, acc1, 0, 0, 0);
    }
    // gates: regs 0..3 = (i,f,g,o)
    float i0 = fsig(acc0[0]), f0 = fsig(acc0[1]);
    float g0 = ftanh(acc0[2]), o0 = fsig(acc0[3]);
    c0 = f0 * c0 + i0 * g0;
    float h0v = o0 * ftanh(c0);
    float i1 = fsig(acc1[0]), f1 = fsig(acc1[1]);
    float g1 = ftanh(acc1[2]), o1 = fsig(acc1[3]);
    c1 = f1 * c1 + i1 * g1;
    float h1v = o1 * ftanh(c1);

    unsigned pk = (unsigned)__half_as_ushort(__float2half(h0v)) |
                  ((unsigned)__half_as_ushort(__float2half(h1v)) << 16);
    STDWCC(hs, ~pk);                       // publish h[t+1]; no wait needed

    cq[m0]     = __float2half(c0);         // c: plain lazy stores
    cq[m0 + 4] = __float2half(c1);

    hq += 65536; hs += 65536; xq += Bc * G4; cq += Bc * Mc;
  }
}

// ---------------------------------------------------------------------------
// k_wall2: Wall[t*B+b][u] = [h;c] @ Wd + bW.
// h read from hx2 (u32 = ~(h[m_lo]|h[m_lo+4]<<16), m_lo = 8*(k2>>2)+(k2&3));
// c read from cx (natural half2 pairs (2k2, 2k2+1)).
// ---------------------------------------------------------------------------
__global__ void k_wall2(const unsigned* __restrict__ Hxu, const __half2* __restrict__ Cx2,
                        const float* __restrict__ Wd, const float* __restrict__ bW,
                        float* __restrict__ Wall) {
  int r0 = blockIdx.x * 32;
  int wv = __builtin_amdgcn_readfirstlane(threadIdx.x >> 6);
  int lane = threadIdx.x & 63;
  int u2 = lane * 2;
  int rbase = r0 + wv * 8;
  float acc[8][2];
#pragma unroll
  for (int i = 0; i < 8; i++) { acc[i][0] = 0.f; acc[i][1] = 0.f; }
#pragma unroll 2
  for (int k2 = 0; k2 < 128; ++k2) {
    int m_lo = 8 * (k2 >> 2) + (k2 & 3);
    float2 wh0 = *(const float2*)(Wd + (size_t)m_lo * Tc + u2);
    float2 wh1 = *(const float2*)(Wd + (size_t)(m_lo + 4) * Tc + u2);
    float2 wc0 = *(const float2*)(Wd + (size_t)(Mc + 2 * k2) * Tc + u2);
    float2 wc1 = *(const float2*)(Wd + (size_t)(Mc + 2 * k2 + 1) * Tc + u2);
#pragma unroll
    for (int i = 0; i < 8; i++) {
      unsigned hraw = ~Hxu[(size_t)(rbase + i) * 128 + 16384 + k2];  // slot t+1
      __half2 hv = __builtin_bit_cast(__half2, hraw);
      __half2 cv = Cx2[(size_t)(rbase + i) * 128 + k2];
      float hlo = __low2float(hv), hhi = __high2float(hv);
      float clo = __low2float(cv), chi = __high2float(cv);
      acc[i][0] += hlo * wh0.x + hhi * wh1.x + clo * wc0.x + chi * wc1.x;
      acc[i][1] += hlo * wh0.y + hhi * wh1.y + clo * wc0.y + chi * wc1.y;
    }
  }
  float bw0 = bW[u2], bw1 = bW[u2 + 1];
#pragma unroll
  for (int i = 0; i < 8; i++) {
    float2 o; o.x = acc[i][0] + bw0; o.y = acc[i][1] + bw1;
    *(float2*)(Wall + (size_t)(rbase + i) * Tc + u2) = o;
  }
}

// ---------------------------------------------------------------------------
// k_attn: logits_n = sum_u (-2 v_u) / (A_u * P_un + 1); softmax; out = X*alpha
// ---------------------------------------------------------------------------
__global__ void k_attn(const float* __restrict__ Wall, const float* __restrict__ PX,
                       const float* __restrict__ vd, const float* __restrict__ X,
                       float* __restrict__ out) {
  __shared__ float4 av[Nc];
  __shared__ float v2s[Nc];
  __shared__ float wred[2][4];
  int b = blockIdx.x & 127, tq = blockIdx.x >> 7;
  int n = threadIdx.x;           // 0..127
  int wv = n >> 6;
  float4 a;
  a.x = __expf(2.f * Wall[((size_t)(tq * 4 + 0) * Bc + b) * Tc + n]);
  a.y = __expf(2.f * Wall[((size_t)(tq * 4 + 1) * Bc + b) * Tc + n]);
  a.z = __expf(2.f * Wall[((size_t)(tq * 4 + 2) * Bc + b) * Tc + n]);
  a.w = __expf(2.f * Wall[((size_t)(tq * 4 + 3) * Bc + b) * Tc + n]);
  av[n] = a;
  v2s[n] = -2.f * vd[n];
  __syncthreads();
  const float* Pb = PX + (size_t)b * Tc * Nc;
  float e0 = 0.f, e1 = 0.f, e2 = 0.f, e3 = 0.f;
#pragma unroll 4
  for (int u = 0; u < Tc; ++u) {
    float P = Pb[(size_t)u * Nc + n];
    float4 au = av[u];
    float v2 = v2s[u];
    e0 = fmaf(v2, frcp(fmaf(au.x, P, 1.f)), e0);
    e1 = fmaf(v2, frcp(fmaf(au.y, P, 1.f)), e1);
    e2 = fmaf(v2, frcp(fmaf(au.z, P, 1.f)), e2);
    e3 = fmaf(v2, frcp(fmaf(au.w, P, 1.f)), e3);
  }
  float e[4] = {e0, e1, e2, e3};
  float M[4], S[4], ex[4];
#pragma unroll
  for (int k = 0; k < 4; ++k) {
    float m = e[k];
#pragma unroll
    for (int off = 32; off > 0; off >>= 1) m = fmaxf(m, __shfl_xor(m, off));
    if ((n & 63) == 0) wred[wv][k] = m;
  }
  __syncthreads();
#pragma unroll
  for (int k = 0; k < 4; ++k) M[k] = fmaxf(wred[0][k], wred[1][k]);
  __syncthreads();
#pragma unroll
  for (int k = 0; k < 4; ++k) {
    ex[k] = __expf(e[k] - M[k]);
    float s = ex[k];
#pragma unroll
    for (int off = 32; off > 0; off >>= 1) s += __shfl_xor(s, off);
    if ((n & 63) == 0) wred[wv][k] = s;
  }
  __syncthreads();
#pragma unroll
  for (int k = 0; k < 4; ++k) S[k] = wred[0][k] + wred[1][k];
#pragma unroll
  for (int k = 0; k < 4; ++k) {
    int t = tq * 4 + k;
    size_t xi = ((size_t)b * Tc + t) * Nc + n;
    out[xi] = X[xi] * (ex[k] * frcp(S[k]));
  }
}

extern "C" void kernel_launch(void* const* d_in, const int* in_sizes, int n_in,
                              void* d_out, int out_size, void* d_ws, size_t ws_size,
                              hipStream_t stream) {
  (void)in_sizes; (void)n_in; (void)out_size; (void)ws_size;
  const float* X  = (const float*)d_in[0];
  const float* h0 = (const float*)d_in[1];
  const float* s0 = (const float*)d_in[2];
  const float* Wx = (const float*)d_in[3];
  const float* Wh = (const float*)d_in[4];
  const float* bb = (const float*)d_in[5];
  const float* Wd = (const float*)d_in[6];
  const float* bW = (const float*)d_in[7];
  const float* Ud = (const float*)d_in[8];
  const float* bU = (const float*)d_in[9];
  const float* vd = (const float*)d_in[10];
  // d_in[11] = bv: softmax(x + const) == softmax(x), no effect on output.
  float* out = (float*)d_out;
  float* ws = (float*)d_ws;

  float* PX       = ws;                          //  2,097,152 f
  float* XWxP     = PX + 2097152;                // 16,777,216 f
  unsigned* hx2   = (unsigned*)(XWxP + 16777216);// 129*16384 u32 (~h pairs)
  __half* cx      = (__half*)(hx2 + 129 * 16384);// 128*32768 halves
  float* Wall     = (float*)(cx + 128 * 32768);  //  2,097,152 f
  __half* wht     = (__half*)(Wall + 2097152);   //   262,144 halves
  // total ~101 MB

  k_prep<<<8768, 256, 0, stream>>>(Wh, h0, wht, hx2);
  k_ux<<<Bc, 256, 0, stream>>>(X, Ud, bU, PX);
  k_xwx2<<<Tc * 4, 256, 0, stream>>>(X, Wx, bb, XWxP);
  k_scan<<<32, 512, 0, stream>>>(wht, XWxP, hx2, cx, s0);
  k_wall2<<<(Tc * Bc) / 32, 256, 0, stream>>>(hx2, (const __half2*)cx, Wd, bW, Wall);
  k_attn<<<Bc * 32, 128, 0, stream>>>(Wall, PX, vd, X, out);
}

// Round 8
// 832.601 us; speedup vs baseline: 2.6721x; 1.1182x over previous
//
#include <hip/hip_runtime.h>
#include <hip/hip_fp16.h>

// Problem dims (fixed)
#define Bc 128   // batch
#define Tc 128   // timesteps
#define Nc 128   // driving series
#define Mc 256   // hidden
#define G4 1024  // 4*M

typedef _Float16 half8 __attribute__((ext_vector_type(8)));
typedef float f32x4 __attribute__((ext_vector_type(4)));
typedef unsigned u32x4 __attribute__((ext_vector_type(4)));

__device__ __forceinline__ float frcp(float x) {
#if __has_builtin(__builtin_amdgcn_rcpf)
  return __builtin_amdgcn_rcpf(x);
#else
  return 1.f / x;
#endif
}
__device__ __forceinline__ float fsig(float x) { return frcp(1.f + __expf(-x)); }
__device__ __forceinline__ float ftanh(float x) {
  float t = __expf(2.f * x);
  return 1.f - 2.f * frcp(t + 1.f);
}

// gfx950: offset:N must precede cache flags
#define LDX4CC(dst, ptr, OFF) \
  asm volatile("global_load_dwordx4 %0, %1, off offset:" #OFF " sc0 sc1" \
               : "=v"(dst) : "v"(ptr))
#define STDWCC(ptr, v_) \
  asm volatile("global_store_dword %0, %1, off sc0 sc1" :: "v"(ptr), "v"(v_))
#define VMCNT0 do { asm volatile("s_waitcnt vmcnt(0)" ::: "memory"); \
                    __builtin_amdgcn_sched_barrier(0); } while (0)

// ---------------------------------------------------------------------------
// k_prep (8768 blocks x 256):
//  bid<512   : pack Wh -> fp16 A-frags, gate-interleaved cols j'=4m+g, and
//              k-pair order (r2, r2+4) matching the B-side u32 (m, m+4) pairs.
//  512..575  : hx2[0] = ~pack(fp16(h0))  (u32 i=4a+d <-> halves (8a+d, 8a+d+4))
//  576..8767 : zero hx2[1..128]  (poll sentinel; re-zeroed EVERY launch)
// ---------------------------------------------------------------------------
__global__ void k_prep(const float* __restrict__ Wh, const float* __restrict__ h0,
                       __half* __restrict__ wht, unsigned* __restrict__ hx2) {
  int bid = blockIdx.x;
  if (bid < 512) {
    int i = bid * 256 + threadIdx.x;       // u32 index in [0, 131072)
    int jt = i >> 11;
    int rem = i & 2047;
    int kt = rem >> 8;
    int rem2 = rem & 255;
    int lane = rem2 >> 2;
    int r2 = rem2 & 3;
    int jp = jt * 16 + (lane & 15);        // permuted col j'
    int g = jp & 3, mcol = jp >> 2;
    int j = g * 256 + mcol;                // original Wh column
    int mk0 = kt * 32 + (lane >> 4) * 8 + r2;   // k-pair (r2, r2+4)
    wht[(size_t)i * 2]     = __float2half(Wh[(size_t)mk0 * G4 + j]);
    wht[(size_t)i * 2 + 1] = __float2half(Wh[(size_t)(mk0 + 4) * G4 + j]);
  } else if (bid < 576) {
    int idx = (bid - 512) * 256 + threadIdx.x;   // 0..16383
    int b = idx >> 7, i = idx & 127;
    int a = i >> 2, d = i & 3;
    unsigned lo = __half_as_ushort(__float2half(h0[(size_t)b * Mc + 8 * a + d]));
    unsigned hi = __half_as_ushort(__float2half(h0[(size_t)b * Mc + 8 * a + d + 4]));
    hx2[idx] = ~(lo | (hi << 16));
  } else {
    int idx = (bid - 576) * 256 + threadIdx.x;   // 0..2097151
    hx2[16384 + idx] = 0u;
  }
}

// ---------------------------------------------------------------------------
// k_ux: PX[b][u][n] = exp(2*(sum_t X[b][t][n]*Ud[t][u] + bU[u]))
// ---------------------------------------------------------------------------
__global__ void k_ux(const float* __restrict__ X, const float* __restrict__ Ud,
                     const float* __restrict__ bU, float* __restrict__ PX) {
  __shared__ float Xl[Tc][Nc];  // 64KB
  int b = blockIdx.x;
  const float* Xb = X + (size_t)b * Tc * Nc;
  for (int i = threadIdx.x; i < Tc * Nc; i += 256) Xl[i >> 7][i & 127] = Xb[i];
  __syncthreads();
  int n = threadIdx.x & 127;
  int uh = __builtin_amdgcn_readfirstlane(threadIdx.x >> 7);
  for (int u0 = uh * 64; u0 < uh * 64 + 64; u0 += 8) {
    float acc[8];
#pragma unroll
    for (int i = 0; i < 8; i++) acc[i] = 0.f;
    for (int tt = 0; tt < Tc; ++tt) {
      float xv = Xl[tt][n];
#pragma unroll
      for (int i = 0; i < 8; i++) acc[i] += xv * Ud[tt * Tc + u0 + i];
    }
#pragma unroll
    for (int i = 0; i < 8; i++)
      PX[((size_t)b * Tc + (u0 + i)) * Nc + n] = __expf(2.f * (acc[i] + bU[u0 + i]));
  }
}

// ---------------------------------------------------------------------------
// k_xwx2: XWxP[t][b][j'] with j' = 4m+g. grid 512 = t(128) x bq(4), 256 thr.
// ---------------------------------------------------------------------------
__global__ __launch_bounds__(256, 2)
void k_xwx2(const float* __restrict__ X, const float* __restrict__ Wx,
            const float* __restrict__ bias, float* __restrict__ XWxP) {
  __shared__ float xl[32][Nc];  // 16KB
  int t = blockIdx.x >> 2;
  int b0 = (blockIdx.x & 3) * 32;
  for (int i = threadIdx.x; i < 32 * Nc; i += 256) {
    int row = i >> 7, n = i & 127;
    xl[row][n] = X[(size_t)(b0 + row) * Tc * Nc + (size_t)t * Nc + n];
  }
  __syncthreads();
  int m = threadIdx.x;
  float acc[32][4];
#pragma unroll
  for (int i = 0; i < 32; i++)
#pragma unroll
    for (int g = 0; g < 4; g++) acc[i][g] = 0.f;
  for (int n = 0; n < Nc; ++n) {
    float wi = Wx[(size_t)n * G4 + m];
    float wf = Wx[(size_t)n * G4 + 256 + m];
    float wg = Wx[(size_t)n * G4 + 512 + m];
    float wo = Wx[(size_t)n * G4 + 768 + m];
#pragma unroll
    for (int i = 0; i < 32; i++) {
      float xv = xl[i][n];
      acc[i][0] += xv * wi; acc[i][1] += xv * wf;
      acc[i][2] += xv * wg; acc[i][3] += xv * wo;
    }
  }
  float bi = bias[m], bf = bias[256 + m], bg = bias[512 + m], bo = bias[768 + m];
#pragma unroll
  for (int i = 0; i < 32; i++) {
    float4 o;
    o.x = acc[i][0] + bi; o.y = acc[i][1] + bf;
    o.z = acc[i][2] + bg; o.w = acc[i][3] + bo;
    *(float4*)(XWxP + ((size_t)t * Bc + b0 + i) * G4 + m * 4) = o;
  }
}

// ---------------------------------------------------------------------------
// k_scan: persistent LSTM scan, 32 blocks x 512 threads. DATA-IS-FLAG sync
// (identical protocol to r7): h stored as ONE dword/lane = ~(h[m]|h[m+4]<<16)
// at hx2[t+1][b][jt0*2+lg] via sc0sc1 (IF$); slot pre-zeroed; consumer polls
// its 8 dwordx4 sc0sc1 loads until every dword != 0, then uses ~data.
// NEW this round: A-fragments PINNED in VGPRs via "+v" keep-alive asm inside
// the loop (r7's VGPR_Count=60 proved the allocator rematerialized the Wh
// loads into the loop); __launch_bounds__(512,2) caps at 256 VGPR.
// ---------------------------------------------------------------------------
__global__ __launch_bounds__(512, 2)
void k_scan(const __half* __restrict__ wht, const float* __restrict__ xwxp,
            unsigned* __restrict__ hx2, __half* __restrict__ cx,
            const float* __restrict__ s0) {
  int bid = blockIdx.x;                 // 32 blocks
  int q = bid >> 3, grp = bid & 7;
  int tid = threadIdx.x;
  int wave = __builtin_amdgcn_readfirstlane(tid >> 6);
  int lane = tid & 63;
  int lb = lane & 15, lg = lane >> 4;
  int b = grp * 16 + lb;
  int jt0 = q * 16 + wave * 2;          // even
  int m0 = jt0 * 4 + lg;

  // persistent A fragments: 64 VGPRs, loaded once
  half8 A0[8], A1[8];
#pragma unroll
  for (int kt = 0; kt < 8; ++kt) {
    A0[kt] = *(const half8*)(wht + ((size_t)(jt0 * 8 + kt) * 64 + lane) * 8);
    A1[kt] = *(const half8*)(wht + ((size_t)((jt0 + 1) * 8 + kt) * 64 + lane) * 8);
  }

  float c0 = s0[(size_t)b * Mc + m0];
  float c1 = s0[(size_t)b * Mc + m0 + 4];

  const char* hq = (const char*)hx2 + ((size_t)b * 128 + lg * 4) * 4;         // read h[t]
  char*       hs = (char*)hx2 + ((size_t)16384 + b * 128 + jt0 * 2 + lg) * 4; // write h[t+1]
  const float* xq = xwxp + ((size_t)b) * G4 + jt0 * 16 + lg * 4;
  __half*      cq = cx + (size_t)b * Mc;

  f32x4 braw[8];

#pragma unroll 1
  for (int t = 0; t < 128; ++t) {
    // PIN: force A-frags to stay register-resident (opaque RMW — the
    // allocator cannot rematerialize the wht loads into the loop).
    asm volatile("" : "+v"(A0[0]), "+v"(A0[1]), "+v"(A0[2]), "+v"(A0[3]),
                      "+v"(A0[4]), "+v"(A0[5]), "+v"(A0[6]), "+v"(A0[7]));
    asm volatile("" : "+v"(A1[0]), "+v"(A1[1]), "+v"(A1[2]), "+v"(A1[3]),
                      "+v"(A1[4]), "+v"(A1[5]), "+v"(A1[6]), "+v"(A1[7]));

    // acc init (plain loads, L2)
    f32x4 acc0 = *(const f32x4*)(xq);
    f32x4 acc1 = *(const f32x4*)(xq + 16);

    // poll-load h[t]: data IS the flag
    LDX4CC(braw[0], hq, 0);   LDX4CC(braw[1], hq, 64);
    LDX4CC(braw[2], hq, 128); LDX4CC(braw[3], hq, 192);
    LDX4CC(braw[4], hq, 256); LDX4CC(braw[5], hq, 320);
    LDX4CC(braw[6], hq, 384); LDX4CC(braw[7], hq, 448);
    for (;;) {
      VMCNT0;
      unsigned mn = 0xFFFFFFFFu;
#pragma unroll
      for (int kt = 0; kt < 8; ++kt) {
        u32x4 u = __builtin_bit_cast(u32x4, braw[kt]);
        mn = min(mn, min(min(u.x, u.y), min(u.z, u.w)));
      }
      if (__builtin_expect(mn != 0u, 1)) break;
      LDX4CC(braw[0], hq, 0);   LDX4CC(braw[1], hq, 64);
      LDX4CC(braw[2], hq, 128); LDX4CC(braw[3], hq, 192);
      LDX4CC(braw[4], hq, 256); LDX4CC(braw[5], hq, 320);
      LDX4CC(braw[6], hq, 384); LDX4CC(braw[7], hq, 448);
    }

#pragma unroll
    for (int kt = 0; kt < 8; ++kt) {
      u32x4 u = ~__builtin_bit_cast(u32x4, braw[kt]);
      half8 Bf = __builtin_bit_cast(half8, u);
      acc0 = __builtin_amdgcn_mfma_f32_16x16x32_f16(A0[kt], Bf, acc0, 0, 0, 0);
      acc1 = __builtin_amdgcn_mfma_f32_16x16x32_f16(A1[kt], Bf, acc1, 0, 0, 0);
    }
    // gates: regs 0..3 = (i,f,g,o)
    float i0 = fsig(acc0[0]), f0 = fsig(acc0[1]);
    float g0 = ftanh(acc0[2]), o0 = fsig(acc0[3]);
    c0 = f0 * c0 + i0 * g0;
    float h0v = o0 * ftanh(c0);
    float i1 = fsig(acc1[0]), f1 = fsig(acc1[1]);
    float g1 = ftanh(acc1[2]), o1 = fsig(acc1[3]);
    c1 = f1 * c1 + i1 * g1;
    float h1v = o1 * ftanh(c1);

    unsigned pk = (unsigned)__half_as_ushort(__float2half(h0v)) |
                  ((unsigned)__half_as_ushort(__float2half(h1v)) << 16);
    STDWCC(hs, ~pk);                       // publish h[t+1]; no wait needed

    cq[m0]     = __float2half(c0);         // c: plain lazy stores
    cq[m0 + 4] = __float2half(c1);

    hq += 65536; hs += 65536; xq += Bc * G4; cq += Bc * Mc;
  }
}

// ---------------------------------------------------------------------------
// k_wall2: Wall[t*B+b][u] = [h;c] @ Wd + bW.
// h read from hx2 (u32 = ~(h[m_lo]|h[m_lo+4]<<16), m_lo = 8*(k2>>2)+(k2&3));
// c read from cx (natural half2 pairs (2k2, 2k2+1)).
// ---------------------------------------------------------------------------
__global__ void k_wall2(const unsigned* __restrict__ Hxu, const __half2* __restrict__ Cx2,
                        const float* __restrict__ Wd, const float* __restrict__ bW,
                        float* __restrict__ Wall) {
  int r0 = blockIdx.x * 32;
  int wv = __builtin_amdgcn_readfirstlane(threadIdx.x >> 6);
  int lane = threadIdx.x & 63;
  int u2 = lane * 2;
  int rbase = r0 + wv * 8;
  float acc[8][2];
#pragma unroll
  for (int i = 0; i < 8; i++) { acc[i][0] = 0.f; acc[i][1] = 0.f; }
#pragma unroll 2
  for (int k2 = 0; k2 < 128; ++k2) {
    int m_lo = 8 * (k2 >> 2) + (k2 & 3);
    float2 wh0 = *(const float2*)(Wd + (size_t)m_lo * Tc + u2);
    float2 wh1 = *(const float2*)(Wd + (size_t)(m_lo + 4) * Tc + u2);
    float2 wc0 = *(const float2*)(Wd + (size_t)(Mc + 2 * k2) * Tc + u2);
    float2 wc1 = *(const float2*)(Wd + (size_t)(Mc + 2 * k2 + 1) * Tc + u2);
#pragma unroll
    for (int i = 0; i < 8; i++) {
      unsigned hraw = ~Hxu[(size_t)(rbase + i) * 128 + 16384 + k2];  // slot t+1
      __half2 hv = __builtin_bit_cast(__half2, hraw);
      __half2 cv = Cx2[(size_t)(rbase + i) * 128 + k2];
      float hlo = __low2float(hv), hhi = __high2float(hv);
      float clo = __low2float(cv), chi = __high2float(cv);
      acc[i][0] += hlo * wh0.x + hhi * wh1.x + clo * wc0.x + chi * wc1.x;
      acc[i][1] += hlo * wh0.y + hhi * wh1.y + clo * wc0.y + chi * wc1.y;
    }
  }
  float bw0 = bW[u2], bw1 = bW[u2 + 1];
#pragma unroll
  for (int i = 0; i < 8; i++) {
    float2 o; o.x = acc[i][0] + bw0; o.y = acc[i][1] + bw1;
    *(float2*)(Wall + (size_t)(rbase + i) * Tc + u2) = o;
  }
}

// ---------------------------------------------------------------------------
// k_attn: logits_n = sum_u (-2 v_u) / (A_u * P_un + 1); softmax; out = X*alpha
// ---------------------------------------------------------------------------
__global__ void k_attn(const float* __restrict__ Wall, const float* __restrict__ PX,
                       const float* __restrict__ vd, const float* __restrict__ X,
                       float* __restrict__ out) {
  __shared__ float4 av[Nc];
  __shared__ float v2s[Nc];
  __shared__ float wred[2][4];
  int b = blockIdx.x & 127, tq = blockIdx.x >> 7;
  int n = threadIdx.x;           // 0..127
  int wv = n >> 6;
  float4 a;
  a.x = __expf(2.f * Wall[((size_t)(tq * 4 + 0) * Bc + b) * Tc + n]);
  a.y = __expf(2.f * Wall[((size_t)(tq * 4 + 1) * Bc + b) * Tc + n]);
  a.z = __expf(2.f * Wall[((size_t)(tq * 4 + 2) * Bc + b) * Tc + n]);
  a.w = __expf(2.f * Wall[((size_t)(tq * 4 + 3) * Bc + b) * Tc + n]);
  av[n] = a;
  v2s[n] = -2.f * vd[n];
  __syncthreads();
  const float* Pb = PX + (size_t)b * Tc * Nc;
  float e0 = 0.f, e1 = 0.f, e2 = 0.f, e3 = 0.f;
#pragma unroll 4
  for (int u = 0; u < Tc; ++u) {
    float P = Pb[(size_t)u * Nc + n];
    float4 au = av[u];
    float v2 = v2s[u];
    e0 = fmaf(v2, frcp(fmaf(au.x, P, 1.f)), e0);
    e1 = fmaf(v2, frcp(fmaf(au.y, P, 1.f)), e1);
    e2 = fmaf(v2, frcp(fmaf(au.z, P, 1.f)), e2);
    e3 = fmaf(v2, frcp(fmaf(au.w, P, 1.f)), e3);
  }
  float e[4] = {e0, e1, e2, e3};
  float M[4], S[4], ex[4];
#pragma unroll
  for (int k = 0; k < 4; ++k) {
    float m = e[k];
#pragma unroll
    for (int off = 32; off > 0; off >>= 1) m = fmaxf(m, __shfl_xor(m, off));
    if ((n & 63) == 0) wred[wv][k] = m;
  }
  __syncthreads();
#pragma unroll
  for (int k = 0; k < 4; ++k) M[k] = fmaxf(wred[0][k], wred[1][k]);
  __syncthreads();
#pragma unroll
  for (int k = 0; k < 4; ++k) {
    ex[k] = __expf(e[k] - M[k]);
    float s = ex[k];
#pragma unroll
    for (int off = 32; off > 0; off >>= 1) s += __shfl_xor(s, off);
    if ((n & 63) == 0) wred[wv][k] = s;
  }
  __syncthreads();
#pragma unroll
  for (int k = 0; k < 4; ++k) S[k] = wred[0][k] + wred[1][k];
#pragma unroll
  for (int k = 0; k < 4; ++k) {
    int t = tq * 4 + k;
    size_t xi = ((size_t)b * Tc + t) * Nc + n;
    out[xi] = X[xi] * (ex[k] * frcp(S[k]));
  }
}

extern "C" void kernel_launch(void* const* d_in, const int* in_sizes, int n_in,
                              void* d_out, int out_size, void* d_ws, size_t ws_size,
                              hipStream_t stream) {
  (void)in_sizes; (void)n_in; (void)out_size; (void)ws_size;
  const float* X  = (const float*)d_in[0];
  const float* h0 = (const float*)d_in[1];
  const float* s0 = (const float*)d_in[2];
  const float* Wx = (const float*)d_in[3];
  const float* Wh = (const float*)d_in[4];
  const float* bb = (const float*)d_in[5];
  const float* Wd = (const float*)d_in[6];
  const float* bW = (const float*)d_in[7];
  const float* Ud = (const float*)d_in[8];
  const float* bU = (const float*)d_in[9];
  const float* vd = (const float*)d_in[10];
  // d_in[11] = bv: softmax(x + const) == softmax(x), no effect on output.
  float* out = (float*)d_out;
  float* ws = (float*)d_ws;

  float* PX       = ws;                          //  2,097,152 f
  float* XWxP     = PX + 2097152;                // 16,777,216 f
  unsigned* hx2   = (unsigned*)(XWxP + 16777216);// 129*16384 u32 (~h pairs)
  __half* cx      = (__half*)(hx2 + 129 * 16384);// 128*32768 halves
  float* Wall     = (float*)(cx + 128 * 32768);  //  2,097,152 f
  __half* wht     = (__half*)(Wall + 2097152);   //   262,144 halves
  // total ~101 MB

  k_prep<<<8768, 256, 0, stream>>>(Wh, h0, wht, hx2);
  k_ux<<<Bc, 256, 0, stream>>>(X, Ud, bU, PX);
  k_xwx2<<<Tc * 4, 256, 0, stream>>>(X, Wx, bb, XWxP);
  k_scan<<<32, 512, 0, stream>>>(wht, XWxP, hx2, cx, s0);
  k_wall2<<<(Tc * Bc) / 32, 256, 0, stream>>>(hx2, (const __half2*)cx, Wd, bW, Wall);
  k_attn<<<Bc * 32, 128, 0, stream>>>(Wall, PX, vd, X, out);
}